// Round 4
// baseline (411.177 us; speedup 1.0000x reference)
//
#include <hip/hip_runtime.h>
#include <stdint.h>
#include <stddef.h>

#define K_DIM 4096
#define N_DIM 4096
#define BM 128
#define BN 128
#define BK 128
#define NITER (K_DIM / BK)   // 32
#define TILE_A (BM * BK)     // 16 KB per LDS buffer

typedef int v4i __attribute__((ext_vector_type(4)));
typedef uint32_t v4u __attribute__((ext_vector_type(4)));

__device__ __forceinline__ void load_lds16(const void* gp, void* lp) {
  __builtin_amdgcn_global_load_lds(
      (__attribute__((address_space(1))) void*)(uintptr_t)gp,
      (__attribute__((address_space(3))) void*)(uintptr_t)lp,
      16, 0, 0);
}

__device__ __forceinline__ uint32_t pack4(int a, int b, int c, int d) {
  return (uint32_t)(uint8_t)a | ((uint32_t)(uint8_t)b << 8) |
         ((uint32_t)(uint8_t)c << 16) | ((uint32_t)(uint8_t)d << 24);
}

// ---------------- Kernel 0: pack + shuffle weight int32 -> int8 frags ------
// Harness materializes int8 input as int32. Repack directly into MFMA
// B-fragment order so the GEMM can load B register-direct (no LDS):
//   chunk t (16 B): lane=t&63, kb=(t>>6)&63, g=t>>12
//   holds W[g*16 + (lane&15)][kb*64 + (lane>>4)*16 .. +16)
__global__ __launch_bounds__(256) void pack_w_shuf(
    const int* __restrict__ w32, v4u* __restrict__ w8) {
  int t = blockIdx.x * 256 + threadIdx.x;  // N*K/16 = 1,048,576 chunks
  int lane = t & 63;
  int kb = (t >> 6) & 63;
  int g = t >> 12;
  int n = g * 16 + (lane & 15);
  int k = kb * 64 + (lane >> 4) * 16;
  const int4* src = (const int4*)(w32 + (size_t)n * K_DIM + k);
  int4 a = src[0], b = src[1], c = src[2], d = src[3];
  v4u o;
  o.x = pack4(a.x, a.y, a.z, a.w);
  o.y = pack4(b.x, b.y, b.z, b.w);
  o.z = pack4(c.x, c.y, c.z, c.w);
  o.w = pack4(d.x, d.y, d.z, d.w);
  w8[t] = o;
}

// ---------------- Kernel 1: quantize fp32 -> int8 --------------------------
// y = clip(rint(x / 0.05f), -128, 127); exact fp32 division + RNE to match
// jnp.round(x / INPUT_SCALE). 16 floats/thread -> one 16 B store.
__global__ __launch_bounds__(256) void quant_kernel(
    const float4* __restrict__ x, v4u* __restrict__ xq, int n16) {
  int i = blockIdx.x * 256 + threadIdx.x;
  if (i >= n16) return;
  v4u o;
#pragma unroll
  for (int j = 0; j < 4; ++j) {
    float4 v = x[i * 4 + j];
    float r0 = fminf(fmaxf(rintf(v.x / 0.05f), -128.f), 127.f);
    float r1 = fminf(fmaxf(rintf(v.y / 0.05f), -128.f), 127.f);
    float r2 = fminf(fmaxf(rintf(v.z / 0.05f), -128.f), 127.f);
    float r3 = fminf(fmaxf(rintf(v.w / 0.05f), -128.f), 127.f);
    o[j] = pack4((int)r0, (int)r1, (int)r2, (int)r3);
  }
  xq[i] = o;
}

// ---------------- Kernel 2: int8 GEMM, AITER-style K-loop ------------------
// 128x128 tile, BK=128, 4 waves 2x2, v_mfma_i32_16x16x64_i8.
// B: register-direct from pre-shuffled global (coalesced 1 KB/wave loads,
//    no LDS, no barrier coupling).
// A: LDS double-buffer, XOR-swizzled (kv_phys = kv ^ (row&7), 0 conflicts),
//    staged via global_load_lds width=16 AFTER the barrier into the other
//    buffer -> every staging load has a full compute phase of slack before
//    the vmcnt(0) drain at the next barrier (the m97-plateau fix).
// C/D: col = lane&15, row = quad*4 + reg (dtype-independent).
__global__ __launch_bounds__(256) void gemm_i8_kernel(
    const int8_t* __restrict__ A,     // [M, K] quantized activations
    const int8_t* __restrict__ Bs,    // shuffled weight fragments
    const float* __restrict__ bias,   // [N]
    float* __restrict__ C,            // [M, N]
    int M) {
  __shared__ __align__(16) int8_t lds_a[2][TILE_A];  // 32 KB

  const int tid  = threadIdx.x;
  const int lane = tid & 63;
  const int wave = tid >> 6;
  const int wm   = wave >> 1;
  const int wn   = wave & 1;
  const int quad = lane >> 4;
  const int lrow = lane & 15;
  const int rx7  = lrow & 7;

  // XCD-aware block swizzle: 4 N-blocks per XCD (B sub-panel 2 MB L2-resident).
  const int bid   = blockIdx.x;
  const int xcd   = bid & 7;
  const int slot  = bid >> 3;
  const int n_blk = xcd * 4 + (slot & 3);
  const int m_blk = slot >> 2;
  const int m0 = m_blk * BM;
  const int n0 = n_blk * BN;

  // A staging: 128 rows x 8 kv-chunks = 1024 chunks of 16 B = 4 issues.
  // chunk c: row = c>>3, src col = ((c&7) ^ (row&7))*16 (swizzle inverse);
  // LDS dst = c*16 (wave-uniform base + lane*16, as required).
  const int8_t* ag[4];
#pragma unroll
  for (int q = 0; q < 4; ++q) {
    int c = q * 256 + tid;
    int row = c >> 3;
    int col = ((c & 7) ^ (row & 7)) << 4;
    ag[q] = A + (size_t)(m0 + row) * K_DIM + col;
  }

  // B fragment pointer: group g0 = n0/16 + wn*4 (wave-uniform) + lane*16.
  // Frag (j, kb) at bp + j*65536 + kb*1024.
  const int8_t* bp = Bs + ((size_t)(n0 / 16 + wn * 4) << 16) + lane * 16;

  v4i acc[4][4] = {};
  v4i bfr[2][2][4];  // [parity][s][j]

  // Prologue: stage A(0) -> buf0, prefetch B(0).
#pragma unroll
  for (int q = 0; q < 4; ++q)
    load_lds16(ag[q], &lds_a[0][(q * 256 + tid) * 16]);
#pragma unroll
  for (int s = 0; s < 2; ++s)
#pragma unroll
    for (int j = 0; j < 4; ++j)
      bfr[0][s][j] = *(const v4i*)(bp + j * 65536 + s * 1024);

#pragma unroll 2
  for (int it = 0; it < NITER; ++it) {
    __syncthreads();  // drains stage(it)/B(it) — issued a full iter ago
    const int p = it & 1;
    if (it < NITER - 1) {
      // Stage A(it+1) into the other buffer; prefetch B(it+1) into regs.
#pragma unroll
      for (int q = 0; q < 4; ++q)
        load_lds16(ag[q] + (size_t)(it + 1) * BK,
                   &lds_a[p ^ 1][(q * 256 + tid) * 16]);
#pragma unroll
      for (int s = 0; s < 2; ++s)
#pragma unroll
        for (int j = 0; j < 4; ++j)
          bfr[p ^ 1][s][j] =
              *(const v4i*)(bp + j * 65536 + ((it + 1) * 2 + s) * 1024);
    }
    const v4i* A4 = (const v4i*)lds_a[p];
#pragma unroll
    for (int s = 0; s < 2; ++s) {
      v4i af[4];
#pragma unroll
      for (int i = 0; i < 4; ++i)
        af[i] = A4[(wm * 64 + i * 16 + lrow) * 8 + ((s * 4 + quad) ^ rx7)];
#pragma unroll
      for (int i = 0; i < 4; ++i)
#pragma unroll
        for (int j = 0; j < 4; ++j)
          acc[i][j] = __builtin_amdgcn_mfma_i32_16x16x64_i8(
              af[i], bfr[p][s][j], acc[i][j], 0, 0, 0);
    }
  }

  // Epilogue: y = 0.01 * acc + bias[n]
#pragma unroll
  for (int j = 0; j < 4; ++j) {
    const int n = n0 + wn * 64 + j * 16 + lrow;
    const float bn = bias[n];
#pragma unroll
    for (int i = 0; i < 4; ++i) {
      const int mb = m0 + wm * 64 + i * 16 + quad * 4;
#pragma unroll
      for (int r = 0; r < 4; ++r)
        C[(size_t)(mb + r) * N_DIM + n] = 0.01f * (float)acc[i][j][r] + bn;
    }
  }
}

extern "C" void kernel_launch(void* const* d_in, const int* in_sizes, int n_in,
                              void* d_out, int out_size, void* d_ws, size_t ws_size,
                              hipStream_t stream) {
  const float* x    = (const float*)d_in[0];
  const int*   w32  = (const int*)d_in[1];   // harness stores int8 input as int32
  const float* bias = (const float*)d_in[2];
  float* out = (float*)d_out;
  const int M = in_sizes[0] / K_DIM;  // 8192

  int8_t* xq = (int8_t*)d_ws;                              // M*K = 33.5 MB
  int8_t* wq = (int8_t*)d_ws + (size_t)M * K_DIM;          // N*K = 16.8 MB

  const int nwchunk = (N_DIM * K_DIM) / 16;  // 1,048,576
  pack_w_shuf<<<nwchunk / 256, 256, 0, stream>>>(w32, (v4u*)wq);

  const int n16 = (M * K_DIM) / 16;
  quant_kernel<<<(n16 + 255) / 256, 256, 0, stream>>>(
      (const float4*)x, (v4u*)xq, n16);

  const int nblocks = (M / BM) * (N_DIM / BN);  // 2048
  gemm_i8_kernel<<<nblocks, 256, 0, stream>>>(xq, wq, bias, out, M);
}